// Round 11
// baseline (389.957 us; speedup 1.0000x reference)
//
#include <hip/hip_runtime.h>

#define BS 16
#define CI 2048
#define NI 16
#define CO 64
#define NO 32
#define KK 2048   // CO*NO
#define NGRP 256  // i-groups; each handled by 4 sibling blocks (batch quarters)

__device__ __forceinline__ void load_lds16(const float* g, float* l) {
    __builtin_amdgcn_global_load_lds(
        (const __attribute__((address_space(1))) void*)g,
        (__attribute__((address_space(3))) void*)l,
        16, 0, 0);
}

#define WAITVM4 asm volatile("s_waitcnt vmcnt(4)" ::: "memory")
#define WAITVM2 asm volatile("s_waitcnt vmcnt(2)" ::: "memory")
#define WAITVM0 asm volatile("s_waitcnt vmcnt(0)" ::: "memory")
#define WAITLGKM asm volatile("s_waitcnt lgkmcnt(0)" ::: "memory")
#define BAR __builtin_amdgcn_s_barrier

// 512 threads, 1024 blocks, 2 blocks/CU (LDS 76 KB). Each block: 4 batches
// (quarter = slot&3) x 8 capsules (i = gid + il*NGRP). Weight staging is
// self-sliced (thread t writes+reads only wbuf[*][k4..k4+3]): no barriers in
// the weight pipeline; own-wave counted vmcnt only. 2-row subtiles, 4-buffer
// rotation (buffer = q&3, compile-time), depth-3 prefetch.
// act in REGISTERS (a4[4], loaded once in prologue -- il-invariant), so the
// vmcnt stream contains ONLY weight global_load_lds: counting stays exact.
// MODE 0: iter1 (uniform route); MODE 1: iter2 (store logits); MODE 2: iter3.
template <int MODE>
__global__ __launch_bounds__(512, 2) void pass_kernel(
    const float* __restrict__ x,      // [BS][CI][NI]
    const float* __restrict__ w,      // [CI][NI][KK]
    const float* __restrict__ act_in, // [BS][KK]
    float* __restrict__ logits,       // [BS][CI][CO]
    float* __restrict__ partials)     // [NGRP][BS][KK]
{
    __shared__ float wbuf[4][2 * KK]; // 64 KB: 4-buffer rotation of 2-row subtiles
    __shared__ float xb[8][4][NI];    // 2 KB
    __shared__ float sm[8 * 65];      // 2 KB (rows 0-3 live, 4-7 scratch)
    __shared__ float lgb[8][256];     // 8 KB: per-il logits (own-slot, t<256)

    const int t = threadIdx.x;        // 0..511
    const int phys = blockIdx.x;
    const int xcd = phys & 7;
    const int slot = phys >> 3;       // 0..127
    const int gid = xcd * 32 + (slot >> 2);  // 0..255; 4 siblings share gid
    const int quarter = slot & 3;     // batches quarter*4 .. quarter*4+3

    const int k4 = 4 * t;             // this thread's k quad
    const int co = t >> 3;            // k4 / 32
    const int j8 = t & 7;             // lane within 8-group sharing co
    const int b0 = t >> 6;            // softmax cell local batch (t<256: 0..3)
    const int cs = t & 63;            // softmax cell co

    // ---- prologue staging (syncthreads drains all counters) ----
    {
        int il = t >> 6, b = (t >> 4) & 3, n = t & 15;
        int i = gid + il * NGRP;
        xb[il][b][n] = x[((size_t)(quarter * 4 + b) * CI + i) * NI + n];
    }
    float4 a4[4];
    if constexpr (MODE != 0) {
#pragma unroll
        for (int b = 0; b < 4; ++b)
            a4[b] = *(const float4*)&act_in[(size_t)(quarter * 4 + b) * KK + k4];
    }
    if constexpr (MODE == 2) {
        if (t < 256) {
#pragma unroll 1
            for (int il = 0; il < 8; ++il)
                lgb[il][t] = logits[((size_t)(quarter * 4 + b0) * CI + (gid + il * NGRP)) * CO + cs];
        }
    }
    __syncthreads();  // x/lg visible; vmcnt/lgkmcnt drained: exact counting starts

    float4 acc[4];
#pragma unroll
    for (int b = 0; b < 4; ++b) acc[b] = make_float4(0.f, 0.f, 0.f, 0.f);

    // subtile s (0..63): capsule s>>3, ni rows 2(s&7), 2(s&7)+1; buffer s&3.
    // 2 x load_lds16 per thread, lane-linear dest (own 16B slice).
    auto issue = [&](int s) {
        int ilp = s >> 3, qp = s & 7;
        const float* gb = w + ((size_t)(gid + ilp * NGRP) * NI + 2 * qp) * KK + k4;
        float* lb = wbuf[s & 3] + k4;
        load_lds16(gb, lb);
        load_lds16(gb + KK, lb + KK);
    };

    auto computesub = [&](int il, int q, float4(&dst)[4]) {
        float4 wA = *(const float4*)&wbuf[q & 3][k4];        // row 2q
        float4 wB = *(const float4*)&wbuf[q & 3][KK + k4];   // row 2q+1
#pragma unroll
        for (int b = 0; b < 4; ++b) {
            float2 xv = *(const float2*)&xb[il][b][2 * q];
            dst[b].x = fmaf(xv.x, wA.x, dst[b].x);
            dst[b].y = fmaf(xv.x, wA.y, dst[b].y);
            dst[b].z = fmaf(xv.x, wA.z, dst[b].z);
            dst[b].w = fmaf(xv.x, wA.w, dst[b].w);
            dst[b].x = fmaf(xv.y, wB.x, dst[b].x);
            dst[b].y = fmaf(xv.y, wB.y, dst[b].y);
            dst[b].z = fmaf(xv.y, wB.z, dst[b].z);
            dst[b].w = fmaf(xv.y, wB.w, dst[b].w);
        }
    };

    issue(0); issue(1); issue(2);   // depth-3 prologue

#pragma unroll 1
    for (int il = 0; il < 8; ++il) {
        float4 v[4];
        if constexpr (MODE != 0) {
#pragma unroll
            for (int b = 0; b < 4; ++b) v[b] = make_float4(0.f, 0.f, 0.f, 0.f);
        }

        // ---- 8 subtiles, NO barriers: own-wave counters only ----
#pragma unroll
        for (int q = 0; q < 8; ++q) {
            if (il == 7 && q == 6)      { WAITVM2; }  // only {62,63} outstanding
            else if (il == 7 && q == 7) { WAITVM0; }
            else                        { WAITVM4; }  // drain s, keep 2 subtiles
            if constexpr (MODE == 0) computesub(il, q, acc);
            else                     computesub(il, q, v);
            WAITLGKM;   // my reads of this buffer retired before its reuse
            if (il != 7 || q <= 4) issue(il * 8 + q + 3);
        }

        if constexpr (MODE != 0) {
            // ---- distances: act from regs; 8-lane reduce; static select ----
            float dpv = 0.f;
#pragma unroll
            for (int b = 0; b < 4; ++b) {
                float d = v[b].x * a4[b].x + v[b].y * a4[b].y +
                          v[b].z * a4[b].z + v[b].w * a4[b].w;
#pragma unroll
                for (int m = 1; m < 8; m <<= 1)
                    d += __shfl_xor(d, m, 8);
                if (j8 == b) dpv = d;
            }
            sm[j8 * 65 + co] = dpv;   // rows 4-7 are scratch, never read
            WAITLGKM;
            BAR();   // sm exchange (weight prefetch stays in flight)

            if (t < 256) {   // ---- softmax over co: one wave per local batch ----
                float l0 = sm[b0 * 65 + cs];
                if constexpr (MODE == 1) lgb[il][t] = l0;   // store at end
                else                     l0 += lgb[il][t];
                float mx = l0;
#pragma unroll
                for (int m = 1; m < 64; m <<= 1)
                    mx = fmaxf(mx, __shfl_xor(mx, m, 64));
                float e = __expf(l0 - mx);
                float s = e;
#pragma unroll
                for (int m = 1; m < 64; m <<= 1)
                    s += __shfl_xor(s, m, 64);
                sm[b0 * 65 + cs] = e / s;
                WAITLGKM;   // wave-uniform branch: waves 0-3 only
            }
            BAR();

            // ---- routed accumulate ----
#pragma unroll
            for (int b = 0; b < 4; ++b) {
                float r = sm[b * 65 + co];
                acc[b].x = fmaf(r, v[b].x, acc[b].x);
                acc[b].y = fmaf(r, v[b].y, acc[b].y);
                acc[b].z = fmaf(r, v[b].z, acc[b].z);
                acc[b].w = fmaf(r, v[b].w, acc[b].w);
            }
            WAITLGKM;
            BAR();   // sm reads done before next il's dpv writes
        }
    }

    // ---- epilogue (vmcnt drained by il=7 q=7's WAITVM0) ----
#pragma unroll
    for (int b = 0; b < 4; ++b)
        *(float4*)&partials[((size_t)gid * BS + quarter * 4 + b) * KK + k4] = acc[b];

    if constexpr (MODE == 1) {
        if (t < 256) {
#pragma unroll 1
            for (int il = 0; il < 8; ++il)
                logits[((size_t)(quarter * 4 + b0) * CI + (gid + il * NGRP)) * CO + cs] = lgb[il][t];
        }
    }
}

// 256 blocks x 128 threads; block owns 128 outputs; 4-way split over NGRP + LDS combine
__global__ __launch_bounds__(128) void reduce_squash(
    const float* __restrict__ partials,
    const float* __restrict__ bias,
    float* __restrict__ act_out, float scale)
{
    __shared__ float4 sred[4][32];
    const int t = threadIdx.x;
    const int blk = blockIdx.x;
    const int lane = t & 31;
    const int gp = t >> 5;
    const int o4 = blk * 128 + lane * 4;
    const int b = o4 >> 11;
    const int kk = o4 & (KK - 1);
    const float* p = partials + (size_t)b * KK + kk;
    const size_t stride = (size_t)BS * KK;

    float4 s = make_float4(0.f, 0.f, 0.f, 0.f);
#pragma unroll 4
    for (int g = gp * 64; g < gp * 64 + 64; ++g) {
        float4 v = *(const float4*)(p + (size_t)g * stride);
        s.x += v.x; s.y += v.y; s.z += v.z; s.w += v.w;
    }
    sred[gp][lane] = s;
    __syncthreads();

    if (t < 32) {
        float4 v0 = sred[0][t], v1 = sred[1][t], v2 = sred[2][t], v3 = sred[3][t];
        float4 v;
        v.x = (v0.x + v1.x) + (v2.x + v3.x);
        v.y = (v0.y + v1.y) + (v2.y + v3.y);
        v.z = (v0.z + v1.z) + (v2.z + v3.z);
        v.w = (v0.w + v1.w) + (v2.w + v3.w);
        const int ot = blk * 128 + t * 4;
        float4 bb = *(const float4*)&bias[ot & (KK - 1)];
        v.x = v.x * scale + bb.x;
        v.y = v.y * scale + bb.y;
        v.z = v.z * scale + bb.z;
        v.w = v.w * scale + bb.w;
        float n2 = v.x * v.x + v.y * v.y + v.z * v.z + v.w * v.w;
#pragma unroll
        for (int m = 1; m < 8; m <<= 1) n2 += __shfl_xor(n2, m, 8);
        float norm = sqrtf(n2);
        float sc = norm / (1.f + n2);
        float4 o = make_float4(v.x * sc, v.y * sc, v.z * sc, v.w * sc);
        *(float4*)&act_out[ot] = o;
    }
}

extern "C" void kernel_launch(void* const* d_in, const int* in_sizes, int n_in,
                              void* d_out, int out_size, void* d_ws, size_t ws_size,
                              hipStream_t stream) {
    const float* x = (const float*)d_in[0];
    const float* w = (const float*)d_in[1];
    const float* bias = (const float*)d_in[2];
    float* out = (float*)d_out;

    char* p = (char*)d_ws;
    float* partials = (float*)p; p += (size_t)NGRP * BS * KK * 4;  // 33.5 MB
    float* logits = (float*)p;   p += (size_t)BS * CI * CO * 4;    // 8 MB
    float* act1 = (float*)p;     p += (size_t)BS * KK * 4;
    float* act2 = (float*)p;

    dim3 blk(512), grid(4 * NGRP);
    pass_kernel<0><<<grid, blk, 0, stream>>>(x, w, nullptr, logits, partials);
    reduce_squash<<<256, 128, 0, stream>>>(partials, bias, act1, 1.0f / (float)CO);
    pass_kernel<1><<<grid, blk, 0, stream>>>(x, w, act1, logits, partials);
    reduce_squash<<<256, 128, 0, stream>>>(partials, bias, act2, 1.0f);
    pass_kernel<2><<<grid, blk, 0, stream>>>(x, w, act2, logits, partials);
    reduce_squash<<<256, 128, 0, stream>>>(partials, bias, out, 1.0f);
}

// Round 12
// 293.283 us; speedup vs baseline: 1.3296x; 1.3296x over previous
//
#include <hip/hip_runtime.h>

#define BS 16
#define CI 2048
#define NI 16
#define CO 64
#define NO 32
#define KK 2048   // CO*NO
#define NGRP 256  // i-groups; pair of blocks (half 0/1) per group shares weights

__device__ __forceinline__ void load_lds16(const float* g, float* l) {
    __builtin_amdgcn_global_load_lds(
        (const __attribute__((address_space(1))) void*)g,
        (__attribute__((address_space(3))) void*)l, 16, 0, 0);
}

#define WAITVM12 asm volatile("s_waitcnt vmcnt(12)" ::: "memory")
#define WAITVM4  asm volatile("s_waitcnt vmcnt(4)" ::: "memory")
#define WAITVM0  asm volatile("s_waitcnt vmcnt(0)" ::: "memory")
#define WAITLGKM asm volatile("s_waitcnt lgkmcnt(0)" ::: "memory")
#define BAR __builtin_amdgcn_s_barrier
#define MEMFENCE asm volatile("" ::: "memory")

__device__ __forceinline__ unsigned bf16rne(float f) {
    unsigned u = __float_as_uint(f);
    return (u + 0x7fffu + ((u >> 16) & 1u)) >> 16;
}
__device__ __forceinline__ unsigned pack2(float lo, float hi) {
    return bf16rne(lo) | (bf16rne(hi) << 16);
}
__device__ __forceinline__ float4 unpack4(uint2 p) {
    float4 r;
    r.x = __uint_as_float(p.x << 16);
    r.y = __uint_as_float(p.x & 0xffff0000u);
    r.z = __uint_as_float(p.y << 16);
    r.w = __uint_as_float(p.y & 0xffff0000u);
    return r;
}

// ---------------- pass 0: weights -> votes(bf16) + uniform-route sums ------
// r9's proven MODE-0 structure: 512 thr, 512 blocks (pairs), self-sliced
// global_load_lds staging (thread t owns wbuf[*][4t..4t+3]), counted vmcnt,
// NO barriers. New: per il, votes packed to bf16 and stored (8 stores/thread,
// fenced), ledger adjusted: next il's q0/q1 wait vmcnt(12) (=8 stores + 1
// quarter in flight), q2/q3 back to vmcnt(4).
__global__ __launch_bounds__(512, 2) void votes_kernel(
    const float* __restrict__ x,      // [BS][CI][NI]
    const float* __restrict__ w,      // [CI][NI][KK]
    unsigned* __restrict__ votes,     // [CI][BS][KK/2] u32 = 2 bf16
    float* __restrict__ partials)     // [NGRP][BS][KK]
{
    __shared__ float wbuf[2][4 * KK]; // 64 KB: double-buffered 4-row quarters
    __shared__ float xb[8][8][NI];    // 4 KB

    const int t = threadIdx.x;
    const int phys = blockIdx.x;
    const int xcd = phys & 7;
    const int slot = phys >> 3;
    const int pairid = xcd * 32 + (slot >> 1);
    const int half = slot & 1;
    const int k4 = 4 * t;

    {   // stage x
        int il = t >> 6, b = (t >> 3) & 7, n0 = (t & 7) * 2;
        int i = pairid + il * NGRP;
        *(float2*)&xb[il][b][n0] =
            *(const float2*)&x[((size_t)(half * 8 + b) * CI + i) * NI + n0];
    }
    __syncthreads();  // drains all counters: exact ledger starts here

    float4 acc[8];
#pragma unroll
    for (int b = 0; b < 8; ++b) acc[b] = make_float4(0.f, 0.f, 0.f, 0.f);

    auto issue = [&](int s) {        // quarter s: capsule s>>2, rows 4(s&3)..+3
        int ilp = s >> 2, qp = s & 3;
        const float* gb = w + ((size_t)(pairid + ilp * NGRP) * NI + qp * 4) * KK + k4;
        float* lb = wbuf[s & 1] + k4;
#pragma unroll
        for (int r = 0; r < 4; ++r)
            load_lds16(gb + (size_t)r * KK, lb + r * KK);
    };

    auto computequarter = [&](int il, int q, float4(&dst)[8]) {
#pragma unroll
        for (int rg = 0; rg < 2; ++rg) {
            float4 wA = *(const float4*)&wbuf[q & 1][(2 * rg) * KK + k4];
            float4 wB = *(const float4*)&wbuf[q & 1][(2 * rg + 1) * KK + k4];
#pragma unroll
            for (int b = 0; b < 8; ++b) {
                float2 xv = *(const float2*)&xb[il][b][q * 4 + 2 * rg];
                dst[b].x = fmaf(xv.x, wA.x, dst[b].x);
                dst[b].y = fmaf(xv.x, wA.y, dst[b].y);
                dst[b].z = fmaf(xv.x, wA.z, dst[b].z);
                dst[b].w = fmaf(xv.x, wA.w, dst[b].w);
                dst[b].x = fmaf(xv.y, wB.x, dst[b].x);
                dst[b].y = fmaf(xv.y, wB.y, dst[b].y);
                dst[b].z = fmaf(xv.y, wB.z, dst[b].z);
                dst[b].w = fmaf(xv.y, wB.w, dst[b].w);
            }
        }
    };

    issue(0); issue(1);

#pragma unroll 1
    for (int il = 0; il < 8; ++il) {
        float4 v[8];
#pragma unroll
        for (int b = 0; b < 8; ++b) v[b] = make_float4(0.f, 0.f, 0.f, 0.f);

#pragma unroll
        for (int q = 0; q < 4; ++q) {
            // ledger: target quarter s=il*4+q; ops issued after it still out:
            // q0/q1 with il>0: {1 quarter, 8 stores} = 12; else 1 quarter = 4.
            if (q < 2) { if (il > 0) { WAITVM12; } else { WAITVM4; } }
            else if (q == 3) { if (il == 7) { WAITVM0; } else { WAITVM4; } }
            else { WAITVM4; }
            computequarter(il, q, v);
            WAITLGKM;   // my LDS reads retired before buffer reuse
            if (il < 7 || q < 2) issue(il * 4 + q + 2);
        }

        // accumulate uniform sum + pack/store bf16 votes (8 stores, fenced)
        const size_t vbase = ((size_t)(pairid + il * NGRP) * BS + half * 8) * (KK / 2) + 2 * t;
#pragma unroll
        for (int b = 0; b < 8; ++b) {
            acc[b].x += v[b].x; acc[b].y += v[b].y;
            acc[b].z += v[b].z; acc[b].w += v[b].w;
            uint2 pk;
            pk.x = pack2(v[b].x, v[b].y);
            pk.y = pack2(v[b].z, v[b].w);
            *(uint2*)&votes[vbase + (size_t)b * (KK / 2)] = pk;
        }
        MEMFENCE;   // pin stores between q3's fence and next il's WAITVM12
    }

#pragma unroll
    for (int b = 0; b < 8; ++b)
        *(float4*)&partials[((size_t)pairid * BS + half * 8 + b) * KK + k4] = acc[b];
}

// ---------------- passes 1/2: routing from bf16 votes ----------------------
// No weights, no FMAs over ni. Per il: votes(8 x uint2)/thread, register
// double-buffer (vA/vB) prefetched one il ahead; act in LDS; logits in regs
// (fully unrolled il -> all static indexing). 66 KB LDS -> 2 blocks/CU.
#define ILBODY(IL, VC, VN)                                                     \
  {                                                                            \
    if ((IL) < 7) {                                                            \
      _Pragma("unroll")                                                        \
      for (int b = 0; b < 8; ++b)                                              \
        VN[b] = *(const uint2*)&votes[((size_t)(pairid + ((IL) + 1) * NGRP) * BS \
                                       + half * 8 + b) * (KK / 2) + 2 * t];    \
    }                                                                          \
    float dpv = 0.f;                                                           \
    _Pragma("unroll")                                                          \
    for (int b = 0; b < 8; ++b) {                                              \
      float4 vb = unpack4(VC[b]);                                              \
      float4 aa = *(const float4*)&actb[b][k4];                                \
      float d = vb.x * aa.x + vb.y * aa.y + vb.z * aa.z + vb.w * aa.w;         \
      d += __shfl_xor(d, 1, 8);                                                \
      d += __shfl_xor(d, 2, 8);                                                \
      d += __shfl_xor(d, 4, 8);                                                \
      if (j8 == b) dpv = d;                                                    \
    }                                                                          \
    sm[j8 * 65 + co] = dpv;                                                    \
    WAITLGKM; BAR();                                                           \
    {                                                                          \
      float l0 = sm[b0 * 65 + cs];                                             \
      if (MODE == 1) lg[(IL)] = l0; else l0 += lg[(IL)];                       \
      float mx = l0;                                                           \
      mx = fmaxf(mx, __shfl_xor(mx, 1, 64));                                   \
      mx = fmaxf(mx, __shfl_xor(mx, 2, 64));                                   \
      mx = fmaxf(mx, __shfl_xor(mx, 4, 64));                                   \
      mx = fmaxf(mx, __shfl_xor(mx, 8, 64));                                   \
      mx = fmaxf(mx, __shfl_xor(mx, 16, 64));                                  \
      mx = fmaxf(mx, __shfl_xor(mx, 32, 64));                                  \
      float e = __expf(l0 - mx);                                               \
      float ssum = e;                                                          \
      ssum += __shfl_xor(ssum, 1, 64);                                         \
      ssum += __shfl_xor(ssum, 2, 64);                                         \
      ssum += __shfl_xor(ssum, 4, 64);                                         \
      ssum += __shfl_xor(ssum, 8, 64);                                         \
      ssum += __shfl_xor(ssum, 16, 64);                                        \
      ssum += __shfl_xor(ssum, 32, 64);                                        \
      sm[b0 * 65 + cs] = e / ssum;                                             \
    }                                                                          \
    WAITLGKM; BAR();                                                           \
    _Pragma("unroll")                                                          \
    for (int b = 0; b < 8; ++b) {                                              \
      float r = sm[b * 65 + co];                                               \
      float4 vb = unpack4(VC[b]);                                              \
      acc[b].x = fmaf(r, vb.x, acc[b].x);                                      \
      acc[b].y = fmaf(r, vb.y, acc[b].y);                                      \
      acc[b].z = fmaf(r, vb.z, acc[b].z);                                      \
      acc[b].w = fmaf(r, vb.w, acc[b].w);                                      \
    }                                                                          \
    WAITLGKM; BAR();                                                           \
  }

template <int MODE>   // 1: iter2 (write logits); 2: iter3 (read logits)
__global__ __launch_bounds__(512, 2) void route_kernel(
    const unsigned* __restrict__ votes,   // [CI][BS][KK/2]
    const float* __restrict__ act_in,     // [BS][KK]
    float* __restrict__ logits,           // [BS][CI][CO]
    float* __restrict__ partials)         // [NGRP][BS][KK]
{
    __shared__ float actb[8][KK];   // 64 KB
    __shared__ float sm[8 * 65];    // 2 KB

    const int t = threadIdx.x;
    const int phys = blockIdx.x;
    const int xcd = phys & 7;
    const int slot = phys >> 3;
    const int pairid = xcd * 32 + (slot >> 1);
    const int half = slot & 1;
    const int k4 = 4 * t;
    const int co = t >> 3;
    const int j8 = t & 7;
    const int b0 = t >> 6;
    const int cs = t & 63;

#pragma unroll
    for (int b = 0; b < 8; ++b)
        *(float4*)&actb[b][k4] =
            *(const float4*)&act_in[(size_t)(half * 8 + b) * KK + k4];

    float lg[8];
    if constexpr (MODE == 2) {
#pragma unroll
        for (int il = 0; il < 8; ++il)
            lg[il] = logits[((size_t)(half * 8 + b0) * CI + (pairid + il * NGRP)) * CO + cs];
    }
    __syncthreads();

    float4 acc[8];
#pragma unroll
    for (int b = 0; b < 8; ++b) acc[b] = make_float4(0.f, 0.f, 0.f, 0.f);

    uint2 vA[8], vB[8];
#pragma unroll
    for (int b = 0; b < 8; ++b)
        vA[b] = *(const uint2*)&votes[((size_t)pairid * BS + half * 8 + b) * (KK / 2) + 2 * t];

    ILBODY(0, vA, vB)
    ILBODY(1, vB, vA)
    ILBODY(2, vA, vB)
    ILBODY(3, vB, vA)
    ILBODY(4, vA, vB)
    ILBODY(5, vB, vA)
    ILBODY(6, vA, vB)
    ILBODY(7, vB, vA)

#pragma unroll
    for (int b = 0; b < 8; ++b)
        *(float4*)&partials[((size_t)pairid * BS + half * 8 + b) * KK + k4] = acc[b];

    if constexpr (MODE == 1) {
#pragma unroll
        for (int il = 0; il < 8; ++il)
            logits[((size_t)(half * 8 + b0) * CI + (pairid + il * NGRP)) * CO + cs] = lg[il];
    }
}

// 256 blocks x 128 threads; 4-way split over NGRP + LDS combine
__global__ __launch_bounds__(128) void reduce_squash(
    const float* __restrict__ partials,
    const float* __restrict__ bias,
    float* __restrict__ act_out, float scale)
{
    __shared__ float4 sred[4][32];
    const int t = threadIdx.x;
    const int blk = blockIdx.x;
    const int lane = t & 31;
    const int gp = t >> 5;
    const int o4 = blk * 128 + lane * 4;
    const int b = o4 >> 11;
    const int kk = o4 & (KK - 1);
    const float* p = partials + (size_t)b * KK + kk;
    const size_t stride = (size_t)BS * KK;

    float4 s = make_float4(0.f, 0.f, 0.f, 0.f);
#pragma unroll 4
    for (int g = gp * 64; g < gp * 64 + 64; ++g) {
        float4 v = *(const float4*)(p + (size_t)g * stride);
        s.x += v.x; s.y += v.y; s.z += v.z; s.w += v.w;
    }
    sred[gp][lane] = s;
    __syncthreads();

    if (t < 32) {
        float4 v0 = sred[0][t], v1 = sred[1][t], v2 = sred[2][t], v3 = sred[3][t];
        float4 v;
        v.x = (v0.x + v1.x) + (v2.x + v3.x);
        v.y = (v0.y + v1.y) + (v2.y + v3.y);
        v.z = (v0.z + v1.z) + (v2.z + v3.z);
        v.w = (v0.w + v1.w) + (v2.w + v3.w);
        const int ot = blk * 128 + t * 4;
        float4 bb = *(const float4*)&bias[ot & (KK - 1)];
        v.x = v.x * scale + bb.x;
        v.y = v.y * scale + bb.y;
        v.z = v.z * scale + bb.z;
        v.w = v.w * scale + bb.w;
        float n2 = v.x * v.x + v.y * v.y + v.z * v.z + v.w * v.w;
#pragma unroll
        for (int m = 1; m < 8; m <<= 1) n2 += __shfl_xor(n2, m, 8);
        float norm = sqrtf(n2);
        float sc = norm / (1.f + n2);
        float4 o = make_float4(v.x * sc, v.y * sc, v.z * sc, v.w * sc);
        *(float4*)&act_out[ot] = o;
    }
}

extern "C" void kernel_launch(void* const* d_in, const int* in_sizes, int n_in,
                              void* d_out, int out_size, void* d_ws, size_t ws_size,
                              hipStream_t stream) {
    const float* x = (const float*)d_in[0];
    const float* w = (const float*)d_in[1];
    const float* bias = (const float*)d_in[2];
    float* out = (float*)d_out;

    char* p = (char*)d_ws;
    unsigned* votes = (unsigned*)p; p += (size_t)CI * BS * KK * 2;   // 134 MB (bf16)
    float* partials = (float*)p;    p += (size_t)NGRP * BS * KK * 4; // 33.5 MB
    float* logits = (float*)p;      p += (size_t)BS * CI * CO * 4;   // 8 MB
    float* act1 = (float*)p;        p += (size_t)BS * KK * 4;
    float* act2 = (float*)p;

    dim3 blk(512), grid(2 * NGRP);
    votes_kernel<<<grid, blk, 0, stream>>>(x, w, votes, partials);
    reduce_squash<<<256, 128, 0, stream>>>(partials, bias, act1, 1.0f / (float)CO);
    route_kernel<1><<<grid, blk, 0, stream>>>(votes, act1, logits, partials);
    reduce_squash<<<256, 128, 0, stream>>>(partials, bias, act2, 1.0f);
    route_kernel<2><<<grid, blk, 0, stream>>>(votes, act2, logits, partials);
    reduce_squash<<<256, 128, 0, stream>>>(partials, bias, out, 1.0f);
}

// Round 13
// 192.865 us; speedup vs baseline: 2.0219x; 1.5207x over previous
//
#include <hip/hip_runtime.h>

#define BS 16
#define CI 2048
#define NI 16
#define CO 64
#define NO 32
#define KK 2048   // CO*NO
#define NGRP 256  // i-groups

__device__ __forceinline__ void load_lds16(const float* g, float* l) {
    __builtin_amdgcn_global_load_lds(
        (const __attribute__((address_space(1))) void*)g,
        (__attribute__((address_space(3))) void*)l, 16, 0, 0);
}

#define WAITVM12 asm volatile("s_waitcnt vmcnt(12)" ::: "memory")
#define WAITVM4  asm volatile("s_waitcnt vmcnt(4)" ::: "memory")
#define WAITVM0  asm volatile("s_waitcnt vmcnt(0)" ::: "memory")
#define WAITLGKM asm volatile("s_waitcnt lgkmcnt(0)" ::: "memory")
#define BAR __builtin_amdgcn_s_barrier
#define MEMFENCE asm volatile("" ::: "memory")

__device__ __forceinline__ unsigned bf16rne(float f) {
    unsigned u = __float_as_uint(f);
    return (u + 0x7fffu + ((u >> 16) & 1u)) >> 16;
}
__device__ __forceinline__ unsigned pack2(float lo, float hi) {
    return bf16rne(lo) | (bf16rne(hi) << 16);
}

// ---------------- pass 0: weights -> votes(bf16) + uniform-route sums ------
// UNCHANGED from r12 (proven): 512 thr, 512 blocks (pairs), self-sliced
// global_load_lds staging, counted vmcnt ledger incl. the 8 vote stores.
__global__ __launch_bounds__(512, 2) void votes_kernel(
    const float* __restrict__ x,      // [BS][CI][NI]
    const float* __restrict__ w,      // [CI][NI][KK]
    unsigned* __restrict__ votes,     // [CI][BS][KK/2] u32 = 2 bf16
    float* __restrict__ partials)     // [NGRP][BS][KK]
{
    __shared__ float wbuf[2][4 * KK];
    __shared__ float xb[8][8][NI];

    const int t = threadIdx.x;
    const int phys = blockIdx.x;
    const int xcd = phys & 7;
    const int slot = phys >> 3;
    const int pairid = xcd * 32 + (slot >> 1);
    const int half = slot & 1;
    const int k4 = 4 * t;

    {
        int il = t >> 6, b = (t >> 3) & 7, n0 = (t & 7) * 2;
        int i = pairid + il * NGRP;
        *(float2*)&xb[il][b][n0] =
            *(const float2*)&x[((size_t)(half * 8 + b) * CI + i) * NI + n0];
    }
    __syncthreads();

    float4 acc[8];
#pragma unroll
    for (int b = 0; b < 8; ++b) acc[b] = make_float4(0.f, 0.f, 0.f, 0.f);

    auto issue = [&](int s) {
        int ilp = s >> 2, qp = s & 3;
        const float* gb = w + ((size_t)(pairid + ilp * NGRP) * NI + qp * 4) * KK + k4;
        float* lb = wbuf[s & 1] + k4;
#pragma unroll
        for (int r = 0; r < 4; ++r)
            load_lds16(gb + (size_t)r * KK, lb + r * KK);
    };

    auto computequarter = [&](int il, int q, float4(&dst)[8]) {
#pragma unroll
        for (int rg = 0; rg < 2; ++rg) {
            float4 wA = *(const float4*)&wbuf[q & 1][(2 * rg) * KK + k4];
            float4 wB = *(const float4*)&wbuf[q & 1][(2 * rg + 1) * KK + k4];
#pragma unroll
            for (int b = 0; b < 8; ++b) {
                float2 xv = *(const float2*)&xb[il][b][q * 4 + 2 * rg];
                dst[b].x = fmaf(xv.x, wA.x, dst[b].x);
                dst[b].y = fmaf(xv.x, wA.y, dst[b].y);
                dst[b].z = fmaf(xv.x, wA.z, dst[b].z);
                dst[b].w = fmaf(xv.x, wA.w, dst[b].w);
                dst[b].x = fmaf(xv.y, wB.x, dst[b].x);
                dst[b].y = fmaf(xv.y, wB.y, dst[b].y);
                dst[b].z = fmaf(xv.y, wB.z, dst[b].z);
                dst[b].w = fmaf(xv.y, wB.w, dst[b].w);
            }
        }
    };

    issue(0); issue(1);

#pragma unroll 1
    for (int il = 0; il < 8; ++il) {
        float4 v[8];
#pragma unroll
        for (int b = 0; b < 8; ++b) v[b] = make_float4(0.f, 0.f, 0.f, 0.f);

#pragma unroll
        for (int q = 0; q < 4; ++q) {
            if (q < 2) { if (il > 0) { WAITVM12; } else { WAITVM4; } }
            else if (q == 3) { if (il == 7) { WAITVM0; } else { WAITVM4; } }
            else { WAITVM4; }
            computequarter(il, q, v);
            WAITLGKM;
            if (il < 7 || q < 2) issue(il * 4 + q + 2);
        }

        const size_t vbase = ((size_t)(pairid + il * NGRP) * BS + half * 8) * (KK / 2) + 2 * t;
#pragma unroll
        for (int b = 0; b < 8; ++b) {
            acc[b].x += v[b].x; acc[b].y += v[b].y;
            acc[b].z += v[b].z; acc[b].w += v[b].w;
            uint2 pk;
            pk.x = pack2(v[b].x, v[b].y);
            pk.y = pack2(v[b].z, v[b].w);
            *(uint2*)&votes[vbase + (size_t)b * (KK / 2)] = pk;
        }
        MEMFENCE;
    }

#pragma unroll
    for (int b = 0; b < 8; ++b)
        *(float4*)&partials[((size_t)pairid * BS + half * 8 + b) * KK + k4] = acc[b];
}

// ---------------- passes 1/2: routing from bf16 votes (v3) -----------------
// 512 thr, 1024 blocks: 4 siblings per i-group, each owns 4 batches
// (quarter). Vote rows are per-batch => quartering has NO fetch overlap.
// Thread: k8 = 8 k's (uint4 16B loads) x 2 batches (bh = t>>8).
// sm double-buffered per il -> only 2 barriers/il. ~70 VGPR, 34 KB LDS.
#define RILBODY(IL, VC, VN)                                                    \
  {                                                                            \
    const int buf = (IL) & 1;                                                  \
    if ((IL) < 7) {                                                            \
      _Pragma("unroll")                                                        \
      for (int lb = 0; lb < 2; ++lb)                                           \
        VN[lb] = *(const uint4*)&votes[((size_t)(gid + ((IL) + 1) * NGRP) * BS \
                                        + bg0 + lb) * (KK / 2) + 4 * ks];      \
    }                                                                          \
    float dv[2];                                                               \
    _Pragma("unroll")                                                          \
    for (int lb = 0; lb < 2; ++lb) {                                           \
      float4 a0 = *(const float4*)&actb[2 * bh + lb][k8];                      \
      float4 a1 = *(const float4*)&actb[2 * bh + lb][k8 + 4];                  \
      float d = __uint_as_float(VC[lb].x << 16) * a0.x                         \
              + __uint_as_float(VC[lb].x & 0xffff0000u) * a0.y                 \
              + __uint_as_float(VC[lb].y << 16) * a0.z                         \
              + __uint_as_float(VC[lb].y & 0xffff0000u) * a0.w                 \
              + __uint_as_float(VC[lb].z << 16) * a1.x                         \
              + __uint_as_float(VC[lb].z & 0xffff0000u) * a1.y                 \
              + __uint_as_float(VC[lb].w << 16) * a1.z                         \
              + __uint_as_float(VC[lb].w & 0xffff0000u) * a1.w;                \
      d += __shfl_xor(d, 1, 4);                                                \
      d += __shfl_xor(d, 2, 4);                                                \
      dv[lb] = d;                                                              \
    }                                                                          \
    if (j4 == 0) sm[buf][(2 * bh) * 65 + co] = dv[0];                          \
    if (j4 == 1) sm[buf][(2 * bh + 1) * 65 + co] = dv[1];                      \
    WAITLGKM; BAR();                                                           \
    if (t < 256) {                                                             \
      float l0 = sm[buf][(t >> 6) * 65 + (t & 63)];                            \
      if (MODE == 1) lg[(IL)] = l0; else l0 += lg[(IL)];                       \
      float mx = l0;                                                           \
      mx = fmaxf(mx, __shfl_xor(mx, 1, 64));                                   \
      mx = fmaxf(mx, __shfl_xor(mx, 2, 64));                                   \
      mx = fmaxf(mx, __shfl_xor(mx, 4, 64));                                   \
      mx = fmaxf(mx, __shfl_xor(mx, 8, 64));                                   \
      mx = fmaxf(mx, __shfl_xor(mx, 16, 64));                                  \
      mx = fmaxf(mx, __shfl_xor(mx, 32, 64));                                  \
      float e = __expf(l0 - mx);                                               \
      float ssum = e;                                                          \
      ssum += __shfl_xor(ssum, 1, 64);                                         \
      ssum += __shfl_xor(ssum, 2, 64);                                         \
      ssum += __shfl_xor(ssum, 4, 64);                                         \
      ssum += __shfl_xor(ssum, 8, 64);                                         \
      ssum += __shfl_xor(ssum, 16, 64);                                        \
      ssum += __shfl_xor(ssum, 32, 64);                                        \
      sm[buf][(t >> 6) * 65 + (t & 63)] = e / ssum;                            \
      WAITLGKM;                                                                \
    }                                                                          \
    BAR();                                                                     \
    _Pragma("unroll")                                                          \
    for (int lb = 0; lb < 2; ++lb) {                                           \
      float r = sm[buf][(2 * bh + lb) * 65 + co];                              \
      acc[2 * lb + 0].x = fmaf(r, __uint_as_float(VC[lb].x << 16), acc[2 * lb + 0].x); \
      acc[2 * lb + 0].y = fmaf(r, __uint_as_float(VC[lb].x & 0xffff0000u), acc[2 * lb + 0].y); \
      acc[2 * lb + 0].z = fmaf(r, __uint_as_float(VC[lb].y << 16), acc[2 * lb + 0].z); \
      acc[2 * lb + 0].w = fmaf(r, __uint_as_float(VC[lb].y & 0xffff0000u), acc[2 * lb + 0].w); \
      acc[2 * lb + 1].x = fmaf(r, __uint_as_float(VC[lb].z << 16), acc[2 * lb + 1].x); \
      acc[2 * lb + 1].y = fmaf(r, __uint_as_float(VC[lb].z & 0xffff0000u), acc[2 * lb + 1].y); \
      acc[2 * lb + 1].z = fmaf(r, __uint_as_float(VC[lb].w << 16), acc[2 * lb + 1].z); \
      acc[2 * lb + 1].w = fmaf(r, __uint_as_float(VC[lb].w & 0xffff0000u), acc[2 * lb + 1].w); \
    }                                                                          \
  }

template <int MODE>   // 1: iter2 (write logits); 2: iter3 (read logits)
__global__ __launch_bounds__(512, 2) void route_kernel(
    const unsigned* __restrict__ votes,   // [CI][BS][KK/2]
    const float* __restrict__ act_in,     // [BS][KK]
    float* __restrict__ logits,           // [BS][CI][CO]
    float* __restrict__ partials)         // [NGRP][BS][KK]
{
    __shared__ float actb[4][KK];   // 32 KB
    __shared__ float sm[2][4 * 65]; // 2 KB, double-buffered per il

    const int t = threadIdx.x;       // 0..511
    const int phys = blockIdx.x;     // 0..1023
    const int xcd = phys & 7;
    const int slot = phys >> 3;      // 0..127
    const int gid = xcd * 32 + (slot >> 2);  // 0..255
    const int quarter = slot & 3;    // batches quarter*4 .. +3

    const int ks = t & 255;          // k-slice
    const int k8 = 8 * ks;
    const int co = ks >> 2;
    const int j4 = ks & 3;
    const int bh = t >> 8;           // 0/1: local batch pair
    const int bg0 = quarter * 4 + 2 * bh;  // first global batch of this thread

    {   // stage act for the 4 local batches
        int br = t >> 7, e0 = (t & 127) * 16;
#pragma unroll
        for (int r = 0; r < 4; ++r)
            *(float4*)&actb[br][e0 + 4 * r] =
                *(const float4*)&act_in[(size_t)(quarter * 4 + br) * KK + e0 + 4 * r];
    }
    float lg[8];
    if constexpr (MODE == 2) {
        if (t < 256) {
#pragma unroll
            for (int il = 0; il < 8; ++il)
                lg[il] = logits[((size_t)(quarter * 4 + (t >> 6)) * CI + (gid + il * NGRP)) * CO + (t & 63)];
        }
    }
    __syncthreads();

    float4 acc[4];
#pragma unroll
    for (int i = 0; i < 4; ++i) acc[i] = make_float4(0.f, 0.f, 0.f, 0.f);

    uint4 vA[2], vB[2];
#pragma unroll
    for (int lb = 0; lb < 2; ++lb)
        vA[lb] = *(const uint4*)&votes[((size_t)gid * BS + bg0 + lb) * (KK / 2) + 4 * ks];

    RILBODY(0, vA, vB)
    RILBODY(1, vB, vA)
    RILBODY(2, vA, vB)
    RILBODY(3, vB, vA)
    RILBODY(4, vA, vB)
    RILBODY(5, vB, vA)
    RILBODY(6, vA, vB)
    RILBODY(7, vB, vA)

#pragma unroll
    for (int lb = 0; lb < 2; ++lb) {
        float* pp = &partials[((size_t)gid * BS + bg0 + lb) * KK + k8];
        *(float4*)pp = acc[2 * lb];
        *(float4*)(pp + 4) = acc[2 * lb + 1];
    }
    if constexpr (MODE == 1) {
        if (t < 256) {
#pragma unroll
            for (int il = 0; il < 8; ++il)
                logits[((size_t)(quarter * 4 + (t >> 6)) * CI + (gid + il * NGRP)) * CO + (t & 63)] = lg[il];
        }
    }
}

// 256 blocks x 128 threads; 4-way split over NGRP + LDS combine
__global__ __launch_bounds__(128) void reduce_squash(
    const float* __restrict__ partials,
    const float* __restrict__ bias,
    float* __restrict__ act_out, float scale)
{
    __shared__ float4 sred[4][32];
    const int t = threadIdx.x;
    const int blk = blockIdx.x;
    const int lane = t & 31;
    const int gp = t >> 5;
    const int o4 = blk * 128 + lane * 4;
    const int b = o4 >> 11;
    const int kk = o4 & (KK - 1);
    const float* p = partials + (size_t)b * KK + kk;
    const size_t stride = (size_t)BS * KK;

    float4 s = make_float4(0.f, 0.f, 0.f, 0.f);
#pragma unroll 4
    for (int g = gp * 64; g < gp * 64 + 64; ++g) {
        float4 v = *(const float4*)(p + (size_t)g * stride);
        s.x += v.x; s.y += v.y; s.z += v.z; s.w += v.w;
    }
    sred[gp][lane] = s;
    __syncthreads();

    if (t < 32) {
        float4 v0 = sred[0][t], v1 = sred[1][t], v2 = sred[2][t], v3 = sred[3][t];
        float4 v;
        v.x = (v0.x + v1.x) + (v2.x + v3.x);
        v.y = (v0.y + v1.y) + (v2.y + v3.y);
        v.z = (v0.z + v1.z) + (v2.z + v3.z);
        v.w = (v0.w + v1.w) + (v2.w + v3.w);
        const int ot = blk * 128 + t * 4;
        float4 bb = *(const float4*)&bias[ot & (KK - 1)];
        v.x = v.x * scale + bb.x;
        v.y = v.y * scale + bb.y;
        v.z = v.z * scale + bb.z;
        v.w = v.w * scale + bb.w;
        float n2 = v.x * v.x + v.y * v.y + v.z * v.z + v.w * v.w;
#pragma unroll
        for (int m = 1; m < 8; m <<= 1) n2 += __shfl_xor(n2, m, 8);
        float norm = sqrtf(n2);
        float sc = norm / (1.f + n2);
        float4 o = make_float4(v.x * sc, v.y * sc, v.z * sc, v.w * sc);
        *(float4*)&act_out[ot] = o;
    }
}

extern "C" void kernel_launch(void* const* d_in, const int* in_sizes, int n_in,
                              void* d_out, int out_size, void* d_ws, size_t ws_size,
                              hipStream_t stream) {
    const float* x = (const float*)d_in[0];
    const float* w = (const float*)d_in[1];
    const float* bias = (const float*)d_in[2];
    float* out = (float*)d_out;

    char* p = (char*)d_ws;
    unsigned* votes = (unsigned*)p; p += (size_t)CI * BS * KK * 2;   // 134 MB (bf16)
    float* partials = (float*)p;    p += (size_t)NGRP * BS * KK * 4; // 33.5 MB
    float* logits = (float*)p;      p += (size_t)BS * CI * CO * 4;   // 8 MB
    float* act1 = (float*)p;        p += (size_t)BS * KK * 4;
    float* act2 = (float*)p;

    votes_kernel<<<2 * NGRP, 512, 0, stream>>>(x, w, votes, partials);
    reduce_squash<<<256, 128, 0, stream>>>(partials, bias, act1, 1.0f / (float)CO);
    route_kernel<1><<<4 * NGRP, 512, 0, stream>>>(votes, act1, logits, partials);
    reduce_squash<<<256, 128, 0, stream>>>(partials, bias, act2, 1.0f);
    route_kernel<2><<<4 * NGRP, 512, 0, stream>>>(votes, act2, logits, partials);
    reduce_squash<<<256, 128, 0, stream>>>(partials, bias, out, 1.0f);
}